// Round 12
// baseline (283.462 us; speedup 1.0000x reference)
//
#include <hip/hip_runtime.h>
#include <stdint.h>

typedef unsigned int u32;
typedef unsigned long long u64;

// key = ((b*512 + z/2)*512 + y/2)*512 + x/2  in [0, 2^29)
// rec = (key<<3)|off. coarse = rec>>24 (8b), fine = (rec>>17)&127 (7b),
// bucket = key>>14 = rec>>17 (15b), local key = key & 0x3FFF (14b).
#define LBITS  14
#define LMASK  ((1u << LBITS) - 1u)
#define NBUCK  (1u << (29 - LBITS))      // 32768 fine buckets
#define BWORDS (1u << (LBITS - 5))       // 512 u32 bitmap words / bucket
#define WPL    (BWORDS / 64)             // 8 words per lane
#define WOPAD  (BWORDS + BWORDS / 32)    // +1 word per 32 -> conflict-free strided access
#define FCAP   256                       // LDS feats slots per bucket (max uc ~180)
#define BPB    4                         // buckets (waves) per 256-thr block
#define TILE_A 4096                      // phase_a / part1 tile (16 rec/thread)
#define S2     8                         // chunks per coarse bucket in part2
#define SCAN_ELEM 2048

__device__ __forceinline__ u32 woidx(u32 w) { return w + (w >> 5); }

__device__ __forceinline__ u32 make_key(int4 c) {
    return ((((u32)c.x * 512u + ((u32)c.w >> 1)) * 512u + ((u32)c.z >> 1)) * 512u)
           + ((u32)c.y >> 1);
}

// ---- phase A: coords -> linrec + per-tile coarse histogram (bin-major matrix)
__global__ void __launch_bounds__(256) phase_a(const int4* __restrict__ coords,
        u32* __restrict__ linrec, u32* __restrict__ histmat, int n, u32 NT) {
    __shared__ u32 h[4 * 256];
    u32 t = threadIdx.x, wave = t >> 6;
    for (u32 j = t; j < 1024u; j += 256u) h[j] = 0u;
    __syncthreads();
    u32 base = blockIdx.x * TILE_A;
    u32 m = min((u32)TILE_A, (u32)n - base);
    for (u32 j = t; j < m; j += 256u) {
        int4 c = coords[base + j];
        u32 key = make_key(c);
        u32 off = ((u32)c.y & 1u) | (((u32)c.z & 1u) << 1) | (((u32)c.w & 1u) << 2);
        u32 rec = (key << 3) | off;
        linrec[base + j] = rec;
        atomicAdd(&h[wave * 256u + (rec >> 24)], 1u);
    }
    __syncthreads();
    histmat[t * NT + blockIdx.x] = h[t] + h[256u + t] + h[512u + t] + h[768u + t];
}

// ---- 2-dispatch hierarchical exclusive scan ----
__global__ void scan_reduce(const u32* __restrict__ data, u32* __restrict__ partial, u32 G) {
    __shared__ u32 s[256];
    u32 t = threadIdx.x;
    u32 base = blockIdx.x * SCAN_ELEM + t * 8u;
    u32 sum = 0;
    #pragma unroll
    for (int j = 0; j < 8; ++j) { u32 idx = base + j; if (idx < G) sum += data[idx]; }
    s[t] = sum; __syncthreads();
    for (int d = 128; d > 0; d >>= 1) { if ((int)t < d) s[t] += s[t + d]; __syncthreads(); }
    if (t == 0) partial[blockIdx.x] = s[0];
}

// apply: each block re-scans the (<=256) partials locally, then scans its chunk.
__global__ void scan_apply2(const u32* __restrict__ data, u32* __restrict__ out,
                            const u32* __restrict__ partial, u32 NB, u32 G,
                            u32* __restrict__ total) {
    __shared__ u32 sp[256];
    __shared__ u32 s[256];
    u32 t = threadIdx.x;
    sp[t] = (t < NB) ? partial[t] : 0u;
    __syncthreads();
    for (int d = 1; d < 256; d <<= 1) {
        u32 add = (t >= (u32)d) ? sp[t - d] : 0u;
        __syncthreads(); sp[t] += add; __syncthreads();
    }
    u32 blkpfx = (blockIdx.x == 0) ? 0u : sp[blockIdx.x - 1];
    if (total && blockIdx.x == 0 && t == 255u) total[0] = sp[255];
    u32 base = blockIdx.x * SCAN_ELEM + t * 8u;
    u32 v[8]; u32 sum = 0;
    #pragma unroll
    for (int j = 0; j < 8; ++j) {
        u32 idx = base + j;
        v[j] = (idx < G) ? data[idx] : 0u;
        sum += v[j];
    }
    s[t] = sum; __syncthreads();
    for (int d = 1; d < 256; d <<= 1) {
        u32 add = (t >= (u32)d) ? s[t - d] : 0u;
        __syncthreads(); s[t] += add; __syncthreads();
    }
    u32 run = s[t] - sum + blkpfx;
    #pragma unroll
    for (int j = 0; j < 8; ++j) {
        u32 idx = base + j;
        if (idx < G) { u32 x = v[j]; out[idx] = run; run += x; }
    }
}

// ---- part1: coarse scatter, bases from scanned histmat, LDS cursors only
__global__ void __launch_bounds__(256) part1(const u32* __restrict__ linrec,
        const u32* __restrict__ histmat, u32* __restrict__ tmp, int n, u32 NT) {
    __shared__ u32 cur[256];
    u32 t = threadIdx.x;
    cur[t] = histmat[t * NT + blockIdx.x];
    __syncthreads();
    u32 base = blockIdx.x * TILE_A;
    u32 m = min((u32)TILE_A, (u32)n - base);
    for (u32 j = t; j < m; j += 256u) {
        u32 rec = linrec[base + j];
        u32 pos = atomicAdd(&cur[rec >> 24], 1u);  // LDS atomic
        tmp[pos] = rec;
    }
}

// ---- part2a: per (coarse, chunk) 128-bin fine histogram -> hist2[(c*128+f)*S2+s]
__global__ void __launch_bounds__(256) part2a(const u32* __restrict__ tmp,
        const u32* __restrict__ histmat, u32* __restrict__ hist2, int n, u32 NT) {
    __shared__ u32 h[4 * 128];
    u32 t = threadIdx.x, wave = t >> 6;
    u32 c = blockIdx.x / S2, s = blockIdx.x % S2;
    for (u32 j = t; j < 512u; j += 256u) h[j] = 0u;
    __syncthreads();
    u32 cs = histmat[c * NT];
    u32 ce = (c == 255u) ? (u32)n : histmat[(c + 1u) * NT];
    u32 L = ce - cs;
    u32 lo = cs + L * s / S2, hi = cs + L * (s + 1u) / S2;
    for (u32 i = lo + t; i < hi; i += 256u)
        atomicAdd(&h[wave * 128u + ((tmp[i] >> 17) & 127u)], 1u);
    __syncthreads();
    if (t < 128u)
        hist2[((c * 128u + t) * S2) + s] = h[t] + h[128u + t] + h[256u + t] + h[384u + t];
}

// ---- part2b: scatter chunk into fine-bucket order using scanned hist2 bases
__global__ void __launch_bounds__(256) part2b(const u32* __restrict__ tmp,
        const u32* __restrict__ histmat, const u32* __restrict__ hist2,
        u32* __restrict__ buckrec, int n, u32 NT) {
    __shared__ u32 cur[128];
    u32 t = threadIdx.x;
    u32 c = blockIdx.x / S2, s = blockIdx.x % S2;
    if (t < 128u) cur[t] = hist2[((c * 128u + t) * S2) + s];
    __syncthreads();
    u32 cs = histmat[c * NT];
    u32 ce = (c == 255u) ? (u32)n : histmat[(c + 1u) * NT];
    u32 L = ce - cs;
    u32 lo = cs + L * s / S2, hi = cs + L * (s + 1u) / S2;
    for (u32 i = lo + t; i < hi; i += 256u) {
        u32 rec = tmp[i];
        u32 pos = atomicAdd(&cur[(rec >> 17) & 127u], 1u);  // LDS atomic
        buckrec[pos] = rec;
    }
}

// ---- pass_dedup: one wave per bucket. Bitmap + full-WOF rank + feats in LDS;
// writes ucount + COMPACT staged unique keys/feats at the bucket's record start.
__global__ void __launch_bounds__(256) pass_dedup(const u32* __restrict__ buckrec,
        const u32* __restrict__ hist2, const float* __restrict__ kern,
        u32* __restrict__ ucount, u32* __restrict__ keys_st,
        float* __restrict__ feats_st, int n) {
    __shared__ u32 bm[BPB][WOPAD];
    __shared__ u32 wo[BPB][WOPAD];
    __shared__ float fl[BPB][FCAP];
    u32 wave = threadIdx.x >> 6, lane = threadIdx.x & 63u;
    u32 bucket = blockIdx.x * BPB + wave;
    u32* B = bm[wave];
    u32* WOF = wo[wave];
    float* F = fl[wave];
    #pragma unroll
    for (int j = 0; j < WPL; ++j) B[woidx(lane * WPL + j)] = 0u;
    for (u32 j = lane; j < FCAP; j += 64u) F[j] = 0.f;
    __syncthreads();
    u32 start = hist2[bucket * S2];
    u32 end = (bucket + 1u < NBUCK) ? hist2[(bucket + 1u) * S2] : (u32)n;
    for (u32 i = start + lane; i < end; i += 64u) {
        u32 lk = (buckrec[i] >> 3) & LMASK;
        atomicOr(&B[woidx(lk >> 5)], 1u << (lk & 31u));
    }
    __syncthreads();
    u32 pc[WPL]; u32 sum = 0;
    #pragma unroll
    for (int j = 0; j < WPL; ++j) { pc[j] = __popc(B[woidx(lane * WPL + j)]); sum += pc[j]; }
    u32 incl = sum;
    #pragma unroll
    for (int d = 1; d < 64; d <<= 1) {
        u32 t = __shfl_up(incl, d);
        if ((int)lane >= d) incl += t;
    }
    u32 lex = incl - sum;                 // lane-exclusive unique offset in bucket
    u32 uc = __shfl(incl, 63);            // bucket total uniques
    u32 e = lex;
    #pragma unroll
    for (int j = 0; j < WPL; ++j) { WOF[woidx(lane * WPL + j)] = e; e += pc[j]; }
    if (lane == 0u) ucount[bucket] = uc;
    __syncthreads();
    bool lds_ok = (uc <= FCAP);
    if (!lds_ok) {                        // rare: zero own staging window first
        for (u32 j = lane; j < uc; j += 64u) feats_st[start + j] = 0.f;
    }
    __syncthreads();                      // uniform barrier
    for (u32 i = start + lane; i < end; i += 64u) {
        u32 rec = buckrec[i];
        u32 off = rec & 7u;
        float contrib = (float)(1u << off) * kern[off];
        u32 lk = (rec >> 3) & LMASK;
        u32 w = lk >> 5, bit = lk & 31u;
        u32 r = WOF[woidx(w)] + (u32)__popc(B[woidx(w)] & ((1u << bit) - 1u));
        if (lds_ok) atomicAdd(&F[r], contrib);
        else        atomicAdd(&feats_st[start + r], contrib);
    }
    __syncthreads();
    // stage compact unique keys in ascending local-key order
    u32 spos = start + lex;
    u32 keyhi = bucket << LBITS;
    #pragma unroll
    for (int j = 0; j < WPL; ++j) {
        u32 bits = B[woidx(lane * WPL + j)];
        u32 kb = keyhi | ((lane * (u32)WPL + (u32)j) << 5);
        while (bits) {
            u32 t = __builtin_ctz(bits);
            bits &= bits - 1u;
            keys_st[spos++] = kb | t;
        }
    }
    if (lds_ok) {
        for (u32 j = lane; j < uc; j += 64u) feats_st[start + j] = F[j];
    }
}

// ---- pass_copy: wave per bucket, staged -> final rank order (pure coalesced copy)
__global__ void __launch_bounds__(256) pass_copy(const u32* __restrict__ keys_st,
        const float* __restrict__ feats_st, const u32* __restrict__ hist2,
        const u32* __restrict__ ucount, const u32* __restrict__ ubase,
        float4* __restrict__ rows, float* __restrict__ feats, int n) {
    u32 wave = threadIdx.x >> 6, lane = threadIdx.x & 63u;
    u32 bucket = blockIdx.x * BPB + wave;
    u32 start = hist2[bucket * S2];
    u32 uc = ucount[bucket];
    u32 base = ubase[bucket];
    for (u32 j = lane; j < uc; j += 64u) {
        u32 key = keys_st[start + j];
        rows[base + j] = make_float4((float)(key >> 27), (float)(key & 511u),
                                     (float)((key >> 9) & 511u),
                                     (float)((key >> 18) & 511u));
        feats[base + j] = feats_st[start + j];
    }
}

// pad rows AND feats in [U, n)
__global__ void pad_fill(float4* __restrict__ rows, float* __restrict__ feats,
                         const u32* __restrict__ counter, int n) {
    int i = blockIdx.x * blockDim.x + threadIdx.x;
    if (i < n && (u32)i >= counter[0]) {
        rows[i] = make_float4(-1.f, -1.f, -1.f, -1.f);
        feats[i] = 0.f;
    }
}

extern "C" void kernel_launch(void* const* d_in, const int* in_sizes, int n_in,
                              void* d_out, int out_size, void* d_ws, size_t ws_size,
                              hipStream_t stream) {
    const int n = in_sizes[0] / 4;               // 4,000,000 points
    const int4* coords = (const int4*)d_in[0];
    const float* kern  = (const float*)d_in[1];
    const u32 NT = ((u32)n + TILE_A - 1) / TILE_A;        // 977 tiles
    const u32 G1 = 256 * NT;                               // histmat entries (250112)
    const u32 G2 = 256 * 128 * S2;                         // hist2 entries (262144)
    const u32 NB1 = (G1 + SCAN_ELEM - 1) / SCAN_ELEM;      // 123
    const u32 NB2 = (G2 + SCAN_ELEM - 1) / SCAN_ELEM;      // 128
    const u32 NB3 = (NBUCK + SCAN_ELEM - 1) / SCAN_ELEM;   // 16

    u32* wsp = (u32*)d_ws;
    u32* linrec  = wsp;                    // n  (reused as buckrec by part2b)
    u32* tmp     = linrec + n;             // n  (coarse-ordered records)
    u32* keys_st = tmp + n;                // n  staged unique keys
    float* feats_st = (float*)(keys_st + n); // n staged feats
    u32* histmat = (u32*)(feats_st + n);   // G1
    u32* hist2   = histmat + G1;           // G2
    u32* ucount  = hist2 + G2;             // NBUCK
    u32* ubase   = ucount + NBUCK;         // NBUCK
    u32* counter = ubase + NBUCK;          // 4
    u32* spart   = counter + 4;            // 256
    u32* buckrec = linrec;

    float4* rows  = (float4*)d_out;                              // n rows
    float*  feats = (float*)((char*)d_out + (size_t)n * 16);     // n fp32

    phase_a<<<NT, 256, 0, stream>>>(coords, linrec, histmat, n, NT);
    scan_reduce<<<NB1, 256, 0, stream>>>(histmat, spart, G1);
    scan_apply2<<<NB1, 256, 0, stream>>>(histmat, histmat, spart, NB1, G1, (u32*)nullptr);
    part1<<<NT, 256, 0, stream>>>(linrec, histmat, tmp, n, NT);
    part2a<<<256 * S2, 256, 0, stream>>>(tmp, histmat, hist2, n, NT);
    scan_reduce<<<NB2, 256, 0, stream>>>(hist2, spart, G2);
    scan_apply2<<<NB2, 256, 0, stream>>>(hist2, hist2, spart, NB2, G2, (u32*)nullptr);
    part2b<<<256 * S2, 256, 0, stream>>>(tmp, histmat, hist2, buckrec, n, NT);
    pass_dedup<<<NBUCK / BPB, 256, 0, stream>>>(buckrec, hist2, kern, ucount,
                                                keys_st, feats_st, n);
    scan_reduce<<<NB3, 256, 0, stream>>>(ucount, spart, NBUCK);
    scan_apply2<<<NB3, 256, 0, stream>>>(ucount, ubase, spart, NB3, NBUCK, counter);
    pass_copy<<<NBUCK / BPB, 256, 0, stream>>>(keys_st, feats_st, hist2, ucount, ubase,
                                               rows, feats, n);
    pad_fill<<<((u32)n + 255) / 256, 256, 0, stream>>>(rows, feats, counter, n);
}